// Round 4
// baseline (440.781 us; speedup 1.0000x reference)
//
#include <hip/hip_runtime.h>

#define BB 4
#define HH 16
#define SS 4096
#define DD 64
#define NB 256   // S / BLK
#define WW 32
#define NEG (-1e30f)
#define LOG2E 1.44269504f

typedef _Float16 half8_t __attribute__((ext_vector_type(8)));
typedef float float4_t __attribute__((ext_vector_type(4)));

#define VT_STRIDE 40  // f16 elems per V^T row; 80B: b128 reads 16B-aligned, conflict-free

static __device__ __forceinline__ unsigned pack2(float a, float b) {
  union { _Float16 h[2]; unsigned u; } x;
  x.h[0] = (_Float16)a;
  x.h[1] = (_Float16)b;
  return x.u;
}

// load 8 consecutive f32, convert (losslessly: values are exact f16) to half8
static __device__ __forceinline__ half8_t cvt8(const float* p) {
  float4_t a = *(const float4_t*)p;
  float4_t b = *(const float4_t*)(p + 4);
  half8_t h;
#pragma unroll
  for (int r = 0; r < 4; ++r) {
    h[r] = (_Float16)a[r];
    h[r + 4] = (_Float16)b[r];
  }
  return h;
}

__global__ __launch_bounds__(256, 4)
void sparse_attn_kernel(const float* __restrict__ Q,
                        const float* __restrict__ K,
                        const float* __restrict__ V,
                        float* __restrict__ O) {
  // V^T staging for a block PAIR: [buf][d'(64)][n(32)] f16, row stride VT_STRIDE
  __shared__ unsigned short vt[2][64 * VT_STRIDE];

  const int bh = blockIdx.y;
  const int i0 = blockIdx.x * 4;
  const int tid = threadIdx.x;
  const int wave = tid >> 6;
  const int lane = tid & 63;
  const int t = lane & 15;  // query col (for S^T) / d' row (for PV)
  const int q = lane >> 4;  // quad

  const size_t base = (size_t)bh * SS * DD;
  const float* Qb = Q + base;
  const float* Kb = K + base;
  const float* Vb = V + base;

  const int i = i0 + wave;  // this wave's query block

  // Q fragments (B-operand x32): lane holds Q[i*16+t][c2*32 + q*8 .. +7]
  const float* qrow = Qb + (size_t)(i * 16 + t) * DD;
  half8_t qf0 = cvt8(qrow + q * 8);
  half8_t qf1 = cvt8(qrow + 32 + q * 8);

  // K-row permutation so S^T lands in x32 B-operand layout:
  // MFMA0 yields pair-keys q*8 + r, MFMA1 pair-keys q*8 + 4 + r.
  const int prow0 = ((t >> 2) << 3) + (t & 3);  // pi0(t)

  float4_t accO[4];  // accO[c][r] = O[t][c*16 + q*4 + r], fp32
#pragma unroll
  for (int c = 0; c < 4; ++c) accO[c] = {0.f, 0.f, 0.f, 0.f};
  float m_run = NEG;
  float l_run = 0.0f;

  const int lo_blk = (i0 - (WW - 1)) > 0 ? (i0 - (WW - 1)) : 0;
  const int PuLo = lo_blk >> 1;
  const int PuHi = (i0 + 3) >> 1;
  const int nit = PuHi - PuLo + 1;

  // V pair staging: thread handles 4 n-rows x 2 d-cols (transpose + f32->f16)
  const int n0s = (tid >> 5) * 4;  // 0,4,...,28
  const int sds = (tid & 31) * 2;  // 0,2,...,62

#define STAGE_PAIR(PP, BUFIDX)                                              \
  {                                                                         \
    const float* vsrc = Vb + (size_t)(PP) * 32 * DD;                        \
    float2 f0 = *(const float2*)(vsrc + (n0s + 0) * DD + sds);              \
    float2 f1 = *(const float2*)(vsrc + (n0s + 1) * DD + sds);              \
    float2 f2 = *(const float2*)(vsrc + (n0s + 2) * DD + sds);              \
    float2 f3 = *(const float2*)(vsrc + (n0s + 3) * DD + sds);              \
    uint2 wlo, whi;                                                         \
    wlo.x = pack2(f0.x, f1.x);                                              \
    wlo.y = pack2(f2.x, f3.x);                                              \
    whi.x = pack2(f0.y, f1.y);                                              \
    whi.y = pack2(f2.y, f3.y);                                              \
    *(uint2*)&vt[BUFIDX][sds * VT_STRIDE + n0s] = wlo;                      \
    *(uint2*)&vt[BUFIDX][(sds + 1) * VT_STRIDE + n0s] = whi;                \
  }

  STAGE_PAIR(PuLo, 0);

  for (int it = 0; it < nit; ++it) {
    const int P = PuLo + it;
    __syncthreads();
    if (it + 1 < nit) STAGE_PAIR(P + 1, (it + 1) & 1);

    // wave processes this pair iff it overlaps [i-31, i]
    if (2 * P + 1 >= i - (WW - 1) && 2 * P <= i) {
      const float* k0 = Kb + (size_t)(P * 32 + prow0) * DD;
      half8_t kf00 = cvt8(k0 + q * 8);
      half8_t kf01 = cvt8(k0 + 32 + q * 8);
      const float* k1 = k0 + 4 * DD;
      half8_t kf10 = cvt8(k1 + q * 8);
      half8_t kf11 = cvt8(k1 + 32 + q * 8);

      float4_t st0 = {0.f, 0.f, 0.f, 0.f};
      float4_t st1 = {0.f, 0.f, 0.f, 0.f};
      st0 = __builtin_amdgcn_mfma_f32_16x16x32_f16(kf00, qf0, st0, 0, 0, 0);
      st0 = __builtin_amdgcn_mfma_f32_16x16x32_f16(kf01, qf1, st0, 0, 0, 0);
      st1 = __builtin_amdgcn_mfma_f32_16x16x32_f16(kf10, qf0, st1, 0, 0, 0);
      st1 = __builtin_amdgcn_mfma_f32_16x16x32_f16(kf11, qf1, st1, 0, 0, 0);

      // lane's key block: jj = 2P + (q>>1); within-block key rows:
      // st0: (q&1)*8 + r, st1: (q&1)*8 + 4 + r
      const int jj = 2 * P + (q >> 1);
      const bool blk_bad = (jj < i - (WW - 1)) || (jj > i);
      const bool diag = (jj == i);
      const int kr = (q & 1) << 3;

      float s0[4], s1[4];
#pragma unroll
      for (int r = 0; r < 4; ++r) {
        s0[r] = st0[r] * 0.125f;
        s1[r] = st1[r] * 0.125f;
        if (blk_bad || (diag && (kr + r > t))) s0[r] = NEG;
        if (blk_bad || (diag && (kr + 4 + r > t))) s1[r] = NEG;
      }

      float vmax = NEG;
#pragma unroll
      for (int r = 0; r < 4; ++r) vmax = fmaxf(vmax, fmaxf(s0[r], s1[r]));
      vmax = fmaxf(vmax, __shfl_xor(vmax, 16));
      vmax = fmaxf(vmax, __shfl_xor(vmax, 32));
      const float m_new = fmaxf(m_run, vmax);
      const float alpha = __builtin_exp2f((m_run - m_new) * LOG2E);

      float p0[4], p1[4];
      float rs = 0.f;
#pragma unroll
      for (int r = 0; r < 4; ++r) {
        p0[r] = __builtin_exp2f((s0[r] - m_new) * LOG2E);
        p1[r] = __builtin_exp2f((s1[r] - m_new) * LOG2E);
        rs += p0[r] + p1[r];
      }
      rs += __shfl_xor(rs, 16);
      rs += __shfl_xor(rs, 32);
      l_run = l_run * alpha + rs;
      m_run = m_new;

      // P^T already in x32 B-operand layout: pb[j] = P^T[q*8+j][t], f16 like ref
      half8_t pb;
#pragma unroll
      for (int r = 0; r < 4; ++r) {
        pb[r] = (_Float16)p0[r];
        pb[r + 4] = (_Float16)p1[r];
      }

      const unsigned short* vbuf = vt[it & 1];
#pragma unroll
      for (int c = 0; c < 4; ++c) {
#pragma unroll
        for (int r = 0; r < 4; ++r) accO[c][r] *= alpha;
        // V^T A-fragment: lane holds V_pair[n = q*8+j][d' = c*16+t]
        half8_t va = *(const half8_t*)&vbuf[(c * 16 + t) * VT_STRIDE + q * 8];
        accO[c] = __builtin_amdgcn_mfma_f32_16x16x32_f16(va, pb, accO[c], 0, 0, 0);
      }
    }
  }

  // epilogue: O[t][d] = accO / l, f32 out
  const float inv_l = 1.0f / l_run;
  float* orow = O + base + (size_t)(i * 16 + t) * DD;
#pragma unroll
  for (int c = 0; c < 4; ++c) {
    float4_t ov;
#pragma unroll
    for (int r = 0; r < 4; ++r) ov[r] = accO[c][r] * inv_l;
    *(float4_t*)(orow + c * 16 + q * 4) = ov;
  }
}

extern "C" void kernel_launch(void* const* d_in, const int* in_sizes, int n_in,
                              void* d_out, int out_size, void* d_ws, size_t ws_size,
                              hipStream_t stream) {
  const float* Q = (const float*)d_in[0];
  const float* K = (const float*)d_in[1];
  const float* V = (const float*)d_in[2];
  float* O = (float*)d_out;
  dim3 grid(NB / 4, BB * HH);
  sparse_attn_kernel<<<grid, dim3(256), 0, stream>>>(Q, K, V, O);
}

// Round 5
// 274.028 us; speedup vs baseline: 1.6085x; 1.6085x over previous
//
#include <hip/hip_runtime.h>

#define SS 4096
#define DD 64
#define WW 32
#define NEG (-1e30f)
#define LOG2E 1.44269504f

typedef _Float16 half8_t __attribute__((ext_vector_type(8)));
typedef float float4_t __attribute__((ext_vector_type(4)));

#define VSTR 40  // V^T slab row stride (f16): 80 B rows, b64-clean, 2-way max
#define KSTR 68  // K slab row stride (f16): 136 B rows, 2-way max on b64 reads

static __device__ __forceinline__ unsigned pack2(float a, float b) {
  union { _Float16 h[2]; unsigned u; } x;
  x.h[0] = (_Float16)a;
  x.h[1] = (_Float16)b;
  return x.u;
}

static __device__ __forceinline__ half8_t cvt8(const float* p) {
  float4_t a = *(const float4_t*)p;
  float4_t b = *(const float4_t*)(p + 4);
  half8_t h;
#pragma unroll
  for (int r = 0; r < 4; ++r) {
    h[r] = (_Float16)a[r];
    h[r + 4] = (_Float16)b[r];
  }
  return h;
}

static __device__ __forceinline__ half8_t lds_frag(const unsigned short* p) {
  union { half8_t h; uint2 u[2]; } x;
  x.u[0] = *(const uint2*)p;
  x.u[1] = *(const uint2*)(p + 4);
  return x.h;
}

__global__ __launch_bounds__(256, 4)
void sparse_attn_kernel(const float* __restrict__ Q,
                        const float* __restrict__ K,
                        const float* __restrict__ V,
                        float* __restrict__ O) {
  // K quad slab: [buf][row(64) * KSTR + d(64)]
  __shared__ __align__(16) unsigned short kl[2][64 * KSTR];
  // V^T pair slabs: [buf][pair][d(64) * VSTR + n(32)]
  __shared__ __align__(16) unsigned short vl[2][2][64 * VSTR];

  // XCD swizzle: each XCD owns 8 consecutive heads -> K/V window L2-resident
  const int lin = blockIdx.x;
  const int xcd = lin & 7;
  const int logical = (lin >> 3) + xcd * ((int)gridDim.x >> 3);
  const int bh = logical >> 6;
  const int i0 = (logical & 63) * 4;

  const int tid = threadIdx.x;
  const int wave = tid >> 6;
  const int lane = tid & 63;
  const int t = lane & 15;
  const int q = lane >> 4;

  const size_t base = (size_t)bh * SS * DD;
  const float* Qb = Q + base;
  const float* Kb = K + base;
  const float* Vb = V + base;

  const int i = i0 + wave;  // this wave's query block

  // Q fragments (B-operand x32): lane holds Q[i*16+t][c2*32 + q*8 .. +7]
  const float* qrow = Qb + (size_t)(i * 16 + t) * DD;
  half8_t qf0 = cvt8(qrow + q * 8);
  half8_t qf1 = cvt8(qrow + 32 + q * 8);

  // K-row permutation: st for group (p,ro) lands directly in PV B-operand layout
  const int prow0 = ((t >> 2) << 3) + (t & 3);

  float4_t accO[4];
#pragma unroll
  for (int c = 0; c < 4; ++c) accO[c] = {0.f, 0.f, 0.f, 0.f};
  float m_run = NEG;
  float l_run = 0.0f;

  const int lo_blk = (i0 - (WW - 1)) > 0 ? (i0 - (WW - 1)) : 0;
  const int Ulo = lo_blk >> 2;
  const int Uhi = (i0 + 3) >> 2;
  const int nit = Uhi - Ulo + 1;  // <= 9 quad-iterations

  // staging decompositions
  const int kr_ = tid >> 2;        // K: row 0..63
  const int kc_ = (tid & 3) * 16;  // K: col group
  const int n0s = (tid >> 5) * 4;  // V: 4 rows of a pair
  const int sds = (tid & 31) * 2;  // V: 2 d-cols

  float4_t kv[4];  // raw K prefetch (16 f32)
  float2 vv[8];    // raw V prefetch (16 f32)

  auto load_raw = [&](int U) {
    const float* ks = Kb + (size_t)(U * 64 + kr_) * DD + kc_;
#pragma unroll
    for (int ii = 0; ii < 4; ++ii) kv[ii] = *(const float4_t*)(ks + ii * 4);
#pragma unroll
    for (int p = 0; p < 2; ++p)
#pragma unroll
      for (int rr = 0; rr < 4; ++rr)
        vv[p * 4 + rr] =
            *(const float2*)(Vb + (size_t)(U * 64 + p * 32 + n0s + rr) * DD + sds);
  };

  auto store_stage = [&](int bf) {
    unsigned short* kd = &kl[bf][kr_ * KSTR + kc_];
#pragma unroll
    for (int ii = 0; ii < 4; ++ii) {
      uint2 w;
      w.x = pack2(kv[ii][0], kv[ii][1]);
      w.y = pack2(kv[ii][2], kv[ii][3]);
      *(uint2*)(kd + ii * 4) = w;
    }
#pragma unroll
    for (int p = 0; p < 2; ++p) {
      uint2 wlo, whi;
      wlo.x = pack2(vv[p * 4 + 0].x, vv[p * 4 + 1].x);
      wlo.y = pack2(vv[p * 4 + 2].x, vv[p * 4 + 3].x);
      whi.x = pack2(vv[p * 4 + 0].y, vv[p * 4 + 1].y);
      whi.y = pack2(vv[p * 4 + 2].y, vv[p * 4 + 3].y);
      *(uint2*)&vl[bf][p][sds * VSTR + n0s] = wlo;
      *(uint2*)&vl[bf][p][(sds + 1) * VSTR + n0s] = whi;
    }
  };

  load_raw(Ulo);

  for (int it = 0; it < nit; ++it) {
    const int U = Ulo + it;
    const int bf = it & 1;
    store_stage(bf);  // raw regs consumed here; safe vs it-2 readers (barrier at it-1)
    __syncthreads();
    if (it + 1 < nit) load_raw(U + 1);  // in flight across the whole compute phase

    if (4 * U >= i - 34) {  // quad overlaps [i-31, i]
      // ---- QK^T: 8 MFMAs over 64 keys ----
      float4_t st[4];
#pragma unroll
      for (int g = 0; g < 4; ++g) st[g] = {0.f, 0.f, 0.f, 0.f};
#pragma unroll
      for (int p = 0; p < 2; ++p) {
#pragma unroll
        for (int ro = 0; ro < 2; ++ro) {
          const int rowb = p * 32 + prow0 + ro * 4;
          const unsigned short* kp = &kl[bf][rowb * KSTR + q * 8];
          half8_t kf0 = lds_frag(kp);
          half8_t kf1 = lds_frag(kp + 32);
          st[p * 2 + ro] =
              __builtin_amdgcn_mfma_f32_16x16x32_f16(kf0, qf0, st[p * 2 + ro], 0, 0, 0);
          st[p * 2 + ro] =
              __builtin_amdgcn_mfma_f32_16x16x32_f16(kf1, qf1, st[p * 2 + ro], 0, 0, 0);
        }
      }

      // ---- mask + single online-softmax round over 64 keys ----
      float s[4][4];
#pragma unroll
      for (int p = 0; p < 2; ++p) {
        const int jj = 4 * U + 2 * p + (q >> 1);
        const bool bad = (jj < i - (WW - 1)) || (jj > i);
        const bool dg = (jj == i);
        const int kr = (q & 1) << 3;
#pragma unroll
        for (int ro = 0; ro < 2; ++ro)
#pragma unroll
          for (int r = 0; r < 4; ++r) {
            float v = st[p * 2 + ro][r] * 0.125f;
            if (bad || (dg && (kr + ro * 4 + r > t))) v = NEG;
            s[p * 2 + ro][r] = v;
          }
      }
      float vmax = NEG;
#pragma unroll
      for (int g = 0; g < 4; ++g)
#pragma unroll
        for (int r = 0; r < 4; ++r) vmax = fmaxf(vmax, s[g][r]);
      vmax = fmaxf(vmax, __shfl_xor(vmax, 16));
      vmax = fmaxf(vmax, __shfl_xor(vmax, 32));
      const float m_new = fmaxf(m_run, vmax);
      const float alpha = __builtin_exp2f((m_run - m_new) * LOG2E);

      float rs = 0.f;
#pragma unroll
      for (int g = 0; g < 4; ++g)
#pragma unroll
        for (int r = 0; r < 4; ++r) {
          s[g][r] = __builtin_exp2f((s[g][r] - m_new) * LOG2E);
          rs += s[g][r];
        }
      rs += __shfl_xor(rs, 16);
      rs += __shfl_xor(rs, 32);
      l_run = l_run * alpha + rs;
      m_run = m_new;

      // P^T already in PV B-operand layout: pb_p[j] = P^T[p*32 + q*8 + j][t]
      half8_t pb0, pb1;
#pragma unroll
      for (int r = 0; r < 4; ++r) {
        pb0[r] = (_Float16)s[0][r];
        pb0[r + 4] = (_Float16)s[1][r];
        pb1[r] = (_Float16)s[2][r];
        pb1[r + 4] = (_Float16)s[3][r];
      }

      // ---- PV: 8 MFMAs ----
      const unsigned short* v0 = vl[bf][0];
      const unsigned short* v1 = vl[bf][1];
#pragma unroll
      for (int c = 0; c < 4; ++c) {
#pragma unroll
        for (int r = 0; r < 4; ++r) accO[c][r] *= alpha;
        half8_t va0 = lds_frag(&v0[(c * 16 + t) * VSTR + q * 8]);
        half8_t va1 = lds_frag(&v1[(c * 16 + t) * VSTR + q * 8]);
        accO[c] = __builtin_amdgcn_mfma_f32_16x16x32_f16(va0, pb0, accO[c], 0, 0, 0);
        accO[c] = __builtin_amdgcn_mfma_f32_16x16x32_f16(va1, pb1, accO[c], 0, 0, 0);
      }
    }
  }

  // epilogue: O[t][d] = accO / l, f32 out
  const float inv_l = 1.0f / l_run;
  float* orow = O + base + (size_t)(i * 16 + t) * DD;
#pragma unroll
  for (int c = 0; c < 4; ++c) {
    float4_t ov;
#pragma unroll
    for (int r = 0; r < 4; ++r) ov[r] = accO[c][r] * inv_l;
    *(float4_t*)(orow + c * 16 + q * 4) = ov;
  }
}

extern "C" void kernel_launch(void* const* d_in, const int* in_sizes, int n_in,
                              void* d_out, int out_size, void* d_ws, size_t ws_size,
                              hipStream_t stream) {
  const float* Q = (const float*)d_in[0];
  const float* K = (const float*)d_in[1];
  const float* V = (const float*)d_in[2];
  float* O = (float*)d_out;
  sparse_attn_kernel<<<dim3(4096), dim3(256), 0, stream>>>(Q, K, V, O);
}